// Round 1
// baseline (191.748 us; speedup 1.0000x reference)
//
#include <hip/hip_runtime.h>
#include <cstdint>
#include <cstddef>

// ============================================================================
// ProposalTargetLayer (MSDN / Faster-RCNN), gfx950.
// Outputs (flat concat, fp32): rois[16,256,5], labels[16,256],
//   bbox_targets[16,256,4], inside_w[16,256,4], outside_w[16,256,4]
//
// Correctness hinges on bit-exact discrete selection:
//  - IoU fp32, reference op order (no fusable a*b+c patterns -> bit-exact).
//  - jax.random via threefry2x32. THREEFRY_PARTITIONABLE=1 = modern JAX
//    default (split: k_i = tf(key,(0,i)); bits = o0^o1 at counter (0,flat_i)).
//    Set to 0 for legacy scheme (iota halves, concat o0|o1). <-- flip here
//    if selection mismatches.
//  - top_k tie-break (lower index first): 64-bit key (valbits<<32)|(~idx),
//    exact bitwise radix-select for the 256th-largest, then rank-by-count.
// ============================================================================

#define THREEFRY_PARTITIONABLE 1

constexpr int kB = 16;
constexpr int kN = 12000;
constexpr int kG = 128;
constexpr int kM = kN + kG;   // 12128
constexpr int kR = 256;
constexpr int kFgQuota = 64;
constexpr unsigned kSeedHi = 0u;
constexpr unsigned kSeedLo = 42u;   // jax.random.key(42)

__device__ __forceinline__ int imin(int a, int b) { return a < b ? a : b; }
__device__ __forceinline__ int imax(int a, int b) { return a > b ? a : b; }

__device__ __forceinline__ unsigned rotl32(unsigned v, int d) {
  return (v << d) | (v >> (32 - d));
}

// Threefry-2x32, 20 rounds, exactly as in jax/_src/prng.py.
__device__ __forceinline__ void tf2x32(unsigned k0, unsigned k1,
                                       unsigned x0, unsigned x1,
                                       unsigned& o0, unsigned& o1) {
  const unsigned k2 = k0 ^ k1 ^ 0x1BD11BDAu;
  x0 += k0; x1 += k1;
#define TF_R(d) x0 += x1; x1 = rotl32(x1, d); x1 ^= x0;
  TF_R(13) TF_R(15) TF_R(26) TF_R(6)
  x0 += k1; x1 += k2 + 1u;
  TF_R(17) TF_R(29) TF_R(16) TF_R(24)
  x0 += k2; x1 += k0 + 2u;
  TF_R(13) TF_R(15) TF_R(26) TF_R(6)
  x0 += k0; x1 += k1 + 3u;
  TF_R(17) TF_R(29) TF_R(16) TF_R(24)
  x0 += k1; x1 += k2 + 4u;
  TF_R(13) TF_R(15) TF_R(26) TF_R(6)
  x0 += k2; x1 += k0 + 5u;
#undef TF_R
  o0 = x0; o1 = x1;
}

// Keys from jax.random.split(key(42)); which=0 -> k1 (r1), which=1 -> k2 (r2).
__device__ __forceinline__ void derive_key(int which, unsigned& ka, unsigned& kb) {
#if THREEFRY_PARTITIONABLE
  tf2x32(kSeedHi, kSeedLo, 0u, (unsigned)which, ka, kb);
#else
  // legacy split: counts [0,1,2,3] -> pairs (0,2),(1,3); concat(o0s, o1s)
  unsigned a0, a1, b0, b1;
  tf2x32(kSeedHi, kSeedLo, 0u, 2u, a0, a1);
  tf2x32(kSeedHi, kSeedLo, 1u, 3u, b0, b1);
  if (which == 0) { ka = a0; kb = b0; } else { ka = a1; kb = b1; }
#endif
}

__device__ __forceinline__ float bits_to_uniform(unsigned bits) {
  return __uint_as_float((bits >> 9) | 0x3f800000u) - 1.0f;
}

// uniform over shape (kB, kM), flat index i.
__device__ __forceinline__ float jax_uniform(unsigned ka, unsigned kb, unsigned i) {
#if THREEFRY_PARTITIONABLE
  unsigned o0, o1;
  tf2x32(ka, kb, 0u, i, o0, o1);
  return bits_to_uniform(o0 ^ o1);
#else
  const unsigned H = (unsigned)(kB * kM) / 2u;  // even size
  unsigned o0, o1;
  if (i < H) { tf2x32(ka, kb, i, i + H, o0, o1); return bits_to_uniform(o0); }
  else       { tf2x32(ka, kb, i - H, i, o0, o1); return bits_to_uniform(o1); }
#endif
}

// ---------------------------------------------------------------------------
// Kernel A: per (b, m): max-IoU + first-argmax over 128 gt; r1/r2; store
// sortable key value-bits for fg (r1) and bg (r2) channels + gt assignment.
// ---------------------------------------------------------------------------
__global__ __launch_bounds__(256) void k_prep(const float* __restrict__ all_rois,
                                              const float* __restrict__ gt_boxes,
                                              int* __restrict__ asgn,
                                              unsigned* __restrict__ vb) {
  __shared__ float sgx0[kG], sgy0[kG], sgx1[kG], sgy1[kG], sga[kG];
  const int b = blockIdx.y;
  const int m = blockIdx.x * 256 + threadIdx.x;
  if (threadIdx.x < kG) {
    const float* gp = gt_boxes + ((size_t)b * kG + threadIdx.x) * 5;
    const float x0 = gp[0], y0 = gp[1], x1 = gp[2], y1 = gp[3];
    sgx0[threadIdx.x] = x0; sgy0[threadIdx.x] = y0;
    sgx1[threadIdx.x] = x1; sgy1[threadIdx.x] = y1;
    sga[threadIdx.x] = ((x1 - x0) + 1.0f) * ((y1 - y0) + 1.0f);
  }
  __syncthreads();
  if (m >= kM) return;

  float bx0, by0, bx1, by1;
  if (m < kN) {
    const float* rp = all_rois + ((size_t)b * kN + m) * 5;
    bx0 = rp[1]; by0 = rp[2]; bx1 = rp[3]; by1 = rp[4];
  } else {
    const int g = m - kN;  // appended gt proposal
    bx0 = sgx0[g]; by0 = sgy0[g]; bx1 = sgx1[g]; by1 = sgy1[g];
  }
  const float areab = ((bx1 - bx0) + 1.0f) * ((by1 - by0) + 1.0f);

  float best = -1.0f;
  int bi = 0;
  for (int g = 0; g < kG; ++g) {
    const float xx0 = fmaxf(bx0, sgx0[g]);
    const float yy0 = fmaxf(by0, sgy0[g]);
    const float xx1 = fminf(bx1, sgx1[g]);
    const float yy1 = fminf(by1, sgy1[g]);
    const float iw = fmaxf((xx1 - xx0) + 1.0f, 0.0f);
    const float ih = fmaxf((yy1 - yy0) + 1.0f, 0.0f);
    const float inter = iw * ih;
    const float iou = inter / ((areab + sga[g]) - inter);
    if (iou > best) { best = iou; bi = g; }  // strict > = first-argmax
  }
  asgn[(size_t)b * kM + m] = bi;

  unsigned k1a, k1b, k2a, k2b;
  derive_key(0, k1a, k1b);
  derive_key(1, k2a, k2b);
  const unsigned i = (unsigned)(b * kM + m);
  const float r1 = jax_uniform(k1a, k1b, i);
  const float r2 = jax_uniform(k2a, k2b, i);
  const bool fg = best >= 0.5f;
  const bool bg = (best < 0.5f) && (best >= 0.0f);
  const float v1 = fg ? (r1 + 2.0f) : r1;
  const float v2 = bg ? (r2 + 2.0f) : r2;
  // nonneg floats: bit pattern is order-isomorphic to value
  vb[(size_t)b * kM + m] = __float_as_uint(v1);
  vb[(size_t)(kB + b) * kM + m] = __float_as_uint(v2);
}

__device__ __forceinline__ int block_reduce_sum(int v, int* s_red, int tid) {
#pragma unroll
  for (int off = 32; off > 0; off >>= 1) v += __shfl_down(v, off, 64);
  __syncthreads();                       // protect s_red reuse across calls
  if ((tid & 63) == 0) s_red[tid >> 6] = v;
  __syncthreads();
  return s_red[0] + s_red[1] + s_red[2] + s_red[3];
}

// ---------------------------------------------------------------------------
// Kernel B: one block per (which, b). Exact top-256 with XLA tie-break via
// 64-bit keys (valbits<<32)|(0xFFFFFFFF - idx): bitwise radix-select for the
// 256th-largest key, gather survivors, rank among 256, emit sorted indices.
// Also emits fg_num/bg_num (count of valbits >= 2.0f).
// ---------------------------------------------------------------------------
__global__ __launch_bounds__(256) void k_topk(const unsigned* __restrict__ vb,
                                              int* __restrict__ topidx,
                                              int* __restrict__ nin) {
  __shared__ unsigned s_vb[kM];                 // 48.5 KB
  __shared__ unsigned long long s_sel[kR];
  __shared__ int s_red[4];
  __shared__ int s_cnt;
  const int which = blockIdx.x;
  const int b = blockIdx.y;
  const int tid = threadIdx.x;
  const unsigned* src = vb + (size_t)(which * kB + b) * kM;

  int local_in = 0;
  for (int m = tid; m < kM; m += 256) {
    const unsigned v = src[m];
    s_vb[m] = v;
    local_in += (v >= 0x40000000u) ? 1 : 0;     // value >= 2.0 <=> in-mask
  }
  const int n_in = block_reduce_sum(local_in, s_red, tid);
  if (tid == 0) nin[which * kB + b] = n_in;

  // radix-select the kR-th largest 64-bit key (keys are pairwise distinct)
  unsigned long long prefix = 0ull;
  int k = kR;
  for (int bit = 63; bit >= 0; --bit) {
    const unsigned long long want = (prefix >> bit) | 1ull;
    int c = 0;
    for (int m = tid; m < kM; m += 256) {
      const unsigned long long key =
          ((unsigned long long)s_vb[m] << 32) | (unsigned)(0xFFFFFFFFu - (unsigned)m);
      c += ((key >> bit) == want) ? 1 : 0;
    }
    c = block_reduce_sum(c, s_red, tid);        // same value in all threads
    if (c >= k) prefix |= (1ull << bit); else k -= c;
  }
  // prefix == exact 256th-largest key; exactly kR keys are >= prefix
  if (tid == 0) s_cnt = 0;
  __syncthreads();
  for (int m = tid; m < kM; m += 256) {
    const unsigned long long key =
        ((unsigned long long)s_vb[m] << 32) | (unsigned)(0xFFFFFFFFu - (unsigned)m);
    if (key >= prefix) {
      const int p = atomicAdd(&s_cnt, 1);
      if (p < kR) s_sel[p] = key;
    }
  }
  __syncthreads();
  const unsigned long long kt = s_sel[tid];
  int rank = 0;
  for (int j = 0; j < kR; ++j) rank += (s_sel[j] > kt) ? 1 : 0;
  const int m_idx = (int)(0xFFFFFFFFu - (unsigned)(kt & 0xFFFFFFFFull));
  topidx[(size_t)(which * kB + b) * kR + rank] = m_idx;
}

// ---------------------------------------------------------------------------
// Kernel C: sampling arithmetic + gathers + bbox transform + outputs.
// ---------------------------------------------------------------------------
__global__ __launch_bounds__(256) void k_finalize(const float* __restrict__ all_rois,
                                                  const float* __restrict__ gt_boxes,
                                                  const int* __restrict__ asgn,
                                                  const int* __restrict__ topidx,
                                                  const int* __restrict__ nin,
                                                  float* __restrict__ out) {
  const int b = blockIdx.x;
  const int pos = threadIdx.x;
  const int fgnum = nin[b];
  const int bgnum = nin[kB + b];
  const int fgc = imin(fgnum, kFgQuota);
  const int bgav = imin(imax(bgnum, 1), kR);
  const int* fgtop = topidx + (size_t)b * kR;
  const int* bgtop = topidx + (size_t)(kB + b) * kR;

  const bool isfg = pos < fgc;
  int keep;
  if (isfg) keep = fgtop[imin(pos, imax(fgc - 1, 0))];
  else      keep = bgtop[(pos - fgc) % bgav];    // pos >= fgc here -> nonneg

  float bx0, by0, bx1, by1;
  if (keep < kN) {
    const float* rp = all_rois + ((size_t)b * kN + keep) * 5;
    bx0 = rp[1]; by0 = rp[2]; bx1 = rp[3]; by1 = rp[4];
  } else {
    const float* gp = gt_boxes + ((size_t)b * kG + (keep - kN)) * 5;
    bx0 = gp[0]; by0 = gp[1]; bx1 = gp[2]; by1 = gp[3];
  }
  const int a = asgn[(size_t)b * kM + keep];
  const float* gp = gt_boxes + ((size_t)b * kG + a) * 5;
  const float gx0 = gp[0], gy0 = gp[1], gx1 = gp[2], gy1 = gp[3];
  const float lab = isfg ? gp[4] : 0.0f;         // gt labels are >= 1
  const float fg4 = (lab > 0.0f) ? 1.0f : 0.0f;

  const float ew = (bx1 - bx0) + 1.0f;
  const float eh = (by1 - by0) + 1.0f;
  const float ecx = bx0 + 0.5f * ew;
  const float ecy = by0 + 0.5f * eh;
  const float gw = (gx1 - gx0) + 1.0f;
  const float gh = (gy1 - gy0) + 1.0f;
  const float gcx = gx0 + 0.5f * gw;
  const float gcy = gy0 + 0.5f * gh;
  const float t0 = ((gcx - ecx) / ew) / 0.1f;    // (t - MEANS) / STDS, MEANS=0
  const float t1 = ((gcy - ecy) / eh) / 0.1f;
  const float t2 = logf(gw / ew) / 0.2f;
  const float t3 = logf(gh / eh) / 0.2f;

  float* o_rois = out;                                   // [B,R,5]
  float* o_lab  = out + (size_t)kB * kR * 5;             // [B,R]
  float* o_tgt  = o_lab + (size_t)kB * kR;               // [B,R,4]
  float* o_iw   = o_tgt + (size_t)kB * kR * 4;           // [B,R,4]
  float* o_ow   = o_iw  + (size_t)kB * kR * 4;           // [B,R,4]
  const size_t p = (size_t)b * kR + pos;
  o_rois[p * 5 + 0] = (float)b;
  o_rois[p * 5 + 1] = bx0;
  o_rois[p * 5 + 2] = by0;
  o_rois[p * 5 + 3] = bx1;
  o_rois[p * 5 + 4] = by1;
  o_lab[p] = lab;
  o_tgt[p * 4 + 0] = t0 * fg4;
  o_tgt[p * 4 + 1] = t1 * fg4;
  o_tgt[p * 4 + 2] = t2 * fg4;
  o_tgt[p * 4 + 3] = t3 * fg4;
  o_iw[p * 4 + 0] = fg4; o_iw[p * 4 + 1] = fg4;
  o_iw[p * 4 + 2] = fg4; o_iw[p * 4 + 3] = fg4;
  o_ow[p * 4 + 0] = fg4; o_ow[p * 4 + 1] = fg4;
  o_ow[p * 4 + 2] = fg4; o_ow[p * 4 + 3] = fg4;
}

extern "C" void kernel_launch(void* const* d_in, const int* in_sizes, int n_in_args,
                              void* d_out, int out_size, void* d_ws, size_t ws_size,
                              hipStream_t stream) {
  (void)in_sizes; (void)n_in_args; (void)out_size; (void)ws_size;
  const float* all_rois = (const float*)d_in[0];  // [16,12000,5] fp32
  const float* gt_boxes = (const float*)d_in[1];  // [16,128,5] fp32
  float* out = (float*)d_out;

  char* ws = (char*)d_ws;                                  // ~2.3 MB used
  int* asgn    = (int*)ws;                                 // kB*kM int
  unsigned* vb = (unsigned*)(ws + (size_t)kB * kM * 4);    // 2*kB*kM uint
  int* nin     = (int*)(ws + (size_t)kB * kM * 4 * 3);     // 2*kB int
  int* topidx  = nin + 64;                                 // 2*kB*kR int

  dim3 gA((kM + 255) / 256, kB);
  k_prep<<<gA, 256, 0, stream>>>(all_rois, gt_boxes, asgn, vb);
  dim3 gB(2, kB);
  k_topk<<<gB, 256, 0, stream>>>(vb, topidx, nin);
  k_finalize<<<kB, kR, 0, stream>>>(all_rois, gt_boxes, asgn, topidx, nin, out);
}

// Round 2
// 104.848 us; speedup vs baseline: 1.8288x; 1.8288x over previous
//
#include <hip/hip_runtime.h>
#include <cstdint>
#include <cstddef>

// ============================================================================
// ProposalTargetLayer (MSDN / Faster-RCNN), gfx950.
// Round 2: replace 64-pass bitwise radix-select (112.8 us) with
// histogram-select (1 global pass + 1 LDS pass + exact rank of ~K+6
// candidates). Selection stays bit-exact:
//  - only in-mask elements (val >= 2.0) are ever selected by the reference
//    sampling arithmetic, so histogram only bins those (monotone mantissa
//    bins [21:11], clamped for the r+2.0 == 3.0 rounding corner);
//  - final ranking uses the same 64-bit key (valbits<<32)|(~idx) => XLA
//    stable top_k tie-break preserved exactly.
// ============================================================================

#define THREEFRY_PARTITIONABLE 1

constexpr int kB = 16;
constexpr int kN = 12000;
constexpr int kG = 128;
constexpr int kM = kN + kG;   // 12128
constexpr int kM4 = kM / 4;   // 3032 (exact)
constexpr int kR = 256;
constexpr int kFgQuota = 64;
constexpr unsigned kSeedHi = 0u;
constexpr unsigned kSeedLo = 42u;   // jax.random.key(42)

__device__ __forceinline__ int imin(int a, int b) { return a < b ? a : b; }
__device__ __forceinline__ int imax(int a, int b) { return a > b ? a : b; }

__device__ __forceinline__ unsigned rotl32(unsigned v, int d) {
  return (v << d) | (v >> (32 - d));
}

// Threefry-2x32, 20 rounds, exactly as in jax/_src/prng.py.
__device__ __forceinline__ void tf2x32(unsigned k0, unsigned k1,
                                       unsigned x0, unsigned x1,
                                       unsigned& o0, unsigned& o1) {
  const unsigned k2 = k0 ^ k1 ^ 0x1BD11BDAu;
  x0 += k0; x1 += k1;
#define TF_R(d) x0 += x1; x1 = rotl32(x1, d); x1 ^= x0;
  TF_R(13) TF_R(15) TF_R(26) TF_R(6)
  x0 += k1; x1 += k2 + 1u;
  TF_R(17) TF_R(29) TF_R(16) TF_R(24)
  x0 += k2; x1 += k0 + 2u;
  TF_R(13) TF_R(15) TF_R(26) TF_R(6)
  x0 += k0; x1 += k1 + 3u;
  TF_R(17) TF_R(29) TF_R(16) TF_R(24)
  x0 += k1; x1 += k2 + 4u;
  TF_R(13) TF_R(15) TF_R(26) TF_R(6)
  x0 += k2; x1 += k0 + 5u;
#undef TF_R
  o0 = x0; o1 = x1;
}

// Keys from jax.random.split(key(42)); which=0 -> k1 (r1), which=1 -> k2 (r2).
// All inputs are literals -> compiler constant-folds the whole hash.
__device__ __forceinline__ void derive_key(int which, unsigned& ka, unsigned& kb) {
#if THREEFRY_PARTITIONABLE
  tf2x32(kSeedHi, kSeedLo, 0u, (unsigned)which, ka, kb);
#else
  unsigned a0, a1, b0, b1;
  tf2x32(kSeedHi, kSeedLo, 0u, 2u, a0, a1);
  tf2x32(kSeedHi, kSeedLo, 1u, 3u, b0, b1);
  if (which == 0) { ka = a0; kb = b0; } else { ka = a1; kb = b1; }
#endif
}

__device__ __forceinline__ float bits_to_uniform(unsigned bits) {
  return __uint_as_float((bits >> 9) | 0x3f800000u) - 1.0f;
}

__device__ __forceinline__ float jax_uniform(unsigned ka, unsigned kb, unsigned i) {
#if THREEFRY_PARTITIONABLE
  unsigned o0, o1;
  tf2x32(ka, kb, 0u, i, o0, o1);
  return bits_to_uniform(o0 ^ o1);
#else
  const unsigned H = (unsigned)(kB * kM) / 2u;
  unsigned o0, o1;
  if (i < H) { tf2x32(ka, kb, i, i + H, o0, o1); return bits_to_uniform(o0); }
  else       { tf2x32(ka, kb, i - H, i, o0, o1); return bits_to_uniform(o1); }
#endif
}

// ---------------------------------------------------------------------------
// Kernel A: per (b, m): max-IoU + first-argmax over 128 gt; r1/r2; store
// sortable value-bits for fg (r1) and bg (r2) channels + gt assignment.
// gt tiles in LDS as float4 + area: 2 LDS reads/iter instead of 5.
// ---------------------------------------------------------------------------
__global__ __launch_bounds__(256) void k_prep(const float* __restrict__ all_rois,
                                              const float* __restrict__ gt_boxes,
                                              int* __restrict__ asgn,
                                              unsigned* __restrict__ vb) {
  __shared__ float4 sg[kG];
  __shared__ float sga[kG];
  const int b = blockIdx.y;
  const int m = blockIdx.x * 256 + threadIdx.x;
  if (threadIdx.x < kG) {
    const float* gp = gt_boxes + ((size_t)b * kG + threadIdx.x) * 5;
    const float x0 = gp[0], y0 = gp[1], x1 = gp[2], y1 = gp[3];
    sg[threadIdx.x] = make_float4(x0, y0, x1, y1);
    sga[threadIdx.x] = ((x1 - x0) + 1.0f) * ((y1 - y0) + 1.0f);
  }
  __syncthreads();
  if (m >= kM) return;

  float bx0, by0, bx1, by1;
  if (m < kN) {
    const float* rp = all_rois + ((size_t)b * kN + m) * 5;
    bx0 = rp[1]; by0 = rp[2]; bx1 = rp[3]; by1 = rp[4];
  } else {
    const float4 g4 = sg[m - kN];
    bx0 = g4.x; by0 = g4.y; bx1 = g4.z; by1 = g4.w;
  }
  const float areab = ((bx1 - bx0) + 1.0f) * ((by1 - by0) + 1.0f);

  float best = -1.0f;
  int bi = 0;
  for (int g = 0; g < kG; ++g) {
    const float4 g4 = sg[g];
    const float xx0 = fmaxf(bx0, g4.x);
    const float yy0 = fmaxf(by0, g4.y);
    const float xx1 = fminf(bx1, g4.z);
    const float yy1 = fminf(by1, g4.w);
    const float iw = fmaxf((xx1 - xx0) + 1.0f, 0.0f);
    const float ih = fmaxf((yy1 - yy0) + 1.0f, 0.0f);
    const float inter = iw * ih;
    const float iou = inter / ((areab + sga[g]) - inter);
    if (iou > best) { best = iou; bi = g; }  // strict > = first-argmax
  }
  asgn[(size_t)b * kM + m] = bi;

  unsigned k1a, k1b, k2a, k2b;
  derive_key(0, k1a, k1b);
  derive_key(1, k2a, k2b);
  const unsigned i = (unsigned)(b * kM + m);
  const float r1 = jax_uniform(k1a, k1b, i);
  const float r2 = jax_uniform(k2a, k2b, i);
  const bool fg = best >= 0.5f;
  const bool bg = (best < 0.5f) && (best >= 0.0f);
  const float v1 = fg ? (r1 + 2.0f) : r1;
  const float v2 = bg ? (r2 + 2.0f) : r2;
  vb[(size_t)b * kM + m] = __float_as_uint(v1);
  vb[(size_t)(kB + b) * kM + m] = __float_as_uint(v2);
}

__device__ __forceinline__ int block_reduce_sum(int v, int* s_red, int tid) {
#pragma unroll
  for (int off = 32; off > 0; off >>= 1) v += __shfl_down(v, off, 64);
  __syncthreads();
  if ((tid & 63) == 0) s_red[tid >> 6] = v;
  __syncthreads();
  return s_red[0] + s_red[1] + s_red[2] + s_red[3];
}

// in-mask bin: monotone in value. v in [0x40000000, 0x40400000] (2.0..3.0).
__device__ __forceinline__ unsigned mask_bin(unsigned v) {
  unsigned bn = (v - 0x40000000u) >> 11;
  return bn > 2047u ? 2047u : bn;   // exact-3.0 corner merges into top bin
}

// ---------------------------------------------------------------------------
// Kernel B: one block per (which, b). Histogram-select the top
// K = min(n_in, quota) in-mask keys (only entries the sampler can read),
// exact rank among ~K+6 candidates with the full 64-bit tie-break key.
// ---------------------------------------------------------------------------
__global__ __launch_bounds__(256) void k_select(const unsigned* __restrict__ vb,
                                                int* __restrict__ topidx,
                                                int* __restrict__ nin) {
  __shared__ uint4 s_vb4[kM4];                  // 48.5 KB staged value-bits
  __shared__ int s_hist[2048];                  // 8 KB
  __shared__ unsigned long long s_cand[1024];   // 8 KB
  __shared__ int s_scan[256];
  __shared__ int s_red[4];
  __shared__ unsigned long long s_wmax[4];
  __shared__ int s_tbin, s_cnt;
  unsigned* s_vb = (unsigned*)s_vb4;

  const int which = blockIdx.x;
  const int b = blockIdx.y;
  const int tid = threadIdx.x;
  const unsigned* src = vb + (size_t)(which * kB + b) * kM;
  int* dst = topidx + (size_t)(which * kB + b) * kR;

  for (int i = tid; i < 2048; i += 256) s_hist[i] = 0;
  if (tid == 0) s_cnt = 0;
  __syncthreads();

  // pass 1: global (uint4) -> LDS stage + in-mask count + histogram
  int local = 0;
  for (int i = tid; i < kM4; i += 256) {
    const uint4 u = ((const uint4*)src)[i];
    s_vb4[i] = u;
#define HBIN(x) if ((x) >= 0x40000000u) { ++local; atomicAdd(&s_hist[mask_bin(x)], 1); }
    HBIN(u.x) HBIN(u.y) HBIN(u.z) HBIN(u.w)
#undef HBIN
  }
  const int n_in = block_reduce_sum(local, s_red, tid);
  if (tid == 0) nin[which * kB + b] = n_in;
  const int quota = (which == 0) ? kFgQuota : kR;
  const int K = imin(n_in, quota);
  __syncthreads();   // histogram + stage visible to all

  if (K == 0) {
    if (which == 0) return;  // fgc==0 -> fg slots never read
    // bg degenerate fallback: reference takes top of UNMASKED r2 -> plain
    // argmax over all keys (practically unreachable; kept for correctness).
    unsigned long long best = 0ull;
    for (int m = tid; m < kM; m += 256) {
      const unsigned long long key =
          ((unsigned long long)s_vb[m] << 32) | (unsigned)(0xFFFFFFFFu - (unsigned)m);
      if (key > best) best = key;
    }
#pragma unroll
    for (int off = 32; off > 0; off >>= 1) {
      const unsigned long long o = __shfl_down(best, off, 64);
      if (o > best) best = o;
    }
    if ((tid & 63) == 0) s_wmax[tid >> 6] = best;
    __syncthreads();
    if (tid == 0) {
      for (int w = 1; w < 4; ++w) if (s_wmax[w] > best) best = s_wmax[w];
      dst[0] = (int)(0xFFFFFFFFu - (unsigned)(best & 0xFFFFFFFFull));
    }
    return;
  }

  // threshold bin: thread t owns descending 8-bin chunk [2040-8t .. 2047-8t]
  const int base = 2048 - 8 * (tid + 1);
  int s = 0;
#pragma unroll
  for (int j = 0; j < 8; ++j) s += s_hist[base + j];
  s_scan[tid] = s;
  __syncthreads();
  for (int off = 1; off < 256; off <<= 1) {   // inclusive scan over chunks
    const int add = (tid >= off) ? s_scan[tid - off] : 0;
    __syncthreads();
    s_scan[tid] += add;
    __syncthreads();
  }
  const int above = s_scan[tid] - s;  // total count in bins above my chunk
  int cum = above;
  for (int j = 7; j >= 0; --j) {      // unique crossing bin: cum < K <= cum+c
    const int c = s_hist[base + j];
    if (cum < K && cum + c >= K) s_tbin = base + j;
    cum += c;
  }
  __syncthreads();
  const unsigned tbin = (unsigned)s_tbin;

  // pass 2 (LDS): collect candidates with bin >= tbin  (~K + lambda≈6)
  for (int m = tid; m < kM; m += 256) {
    const unsigned v = s_vb[m];
    if (v >= 0x40000000u && mask_bin(v) >= tbin) {
      const int p = atomicAdd(&s_cnt, 1);
      if (p < 1024)
        s_cand[p] = ((unsigned long long)v << 32) | (unsigned)(0xFFFFFFFFu - (unsigned)m);
    }
  }
  __syncthreads();
  const int Nc = imin(s_cnt, 1024);

  // exact rank among candidates (keys pairwise distinct)
  for (int j = tid; j < Nc; j += 256) {
    const unsigned long long key = s_cand[j];
    int rank = 0;
    for (int i = 0; i < Nc; ++i) rank += (s_cand[i] > key) ? 1 : 0;
    if (rank < K)
      dst[rank] = (int)(0xFFFFFFFFu - (unsigned)(key & 0xFFFFFFFFull));
  }
}

// ---------------------------------------------------------------------------
// Kernel C: sampling arithmetic + gathers + bbox transform + outputs.
// ---------------------------------------------------------------------------
__global__ __launch_bounds__(256) void k_finalize(const float* __restrict__ all_rois,
                                                  const float* __restrict__ gt_boxes,
                                                  const int* __restrict__ asgn,
                                                  const int* __restrict__ topidx,
                                                  const int* __restrict__ nin,
                                                  float* __restrict__ out) {
  const int b = blockIdx.x;
  const int pos = threadIdx.x;
  const int fgnum = nin[b];
  const int bgnum = nin[kB + b];
  const int fgc = imin(fgnum, kFgQuota);
  const int bgav = imin(imax(bgnum, 1), kR);
  const int* fgtop = topidx + (size_t)b * kR;
  const int* bgtop = topidx + (size_t)(kB + b) * kR;

  const bool isfg = pos < fgc;
  int keep;
  if (isfg) keep = fgtop[imin(pos, imax(fgc - 1, 0))];
  else      keep = bgtop[(pos - fgc) % bgav];

  float bx0, by0, bx1, by1;
  if (keep < kN) {
    const float* rp = all_rois + ((size_t)b * kN + keep) * 5;
    bx0 = rp[1]; by0 = rp[2]; bx1 = rp[3]; by1 = rp[4];
  } else {
    const float* gp = gt_boxes + ((size_t)b * kG + (keep - kN)) * 5;
    bx0 = gp[0]; by0 = gp[1]; bx1 = gp[2]; by1 = gp[3];
  }
  const int a = asgn[(size_t)b * kM + keep];
  const float* gp = gt_boxes + ((size_t)b * kG + a) * 5;
  const float gx0 = gp[0], gy0 = gp[1], gx1 = gp[2], gy1 = gp[3];
  const float lab = isfg ? gp[4] : 0.0f;
  const float fg4 = (lab > 0.0f) ? 1.0f : 0.0f;

  const float ew = (bx1 - bx0) + 1.0f;
  const float eh = (by1 - by0) + 1.0f;
  const float ecx = bx0 + 0.5f * ew;
  const float ecy = by0 + 0.5f * eh;
  const float gw = (gx1 - gx0) + 1.0f;
  const float gh = (gy1 - gy0) + 1.0f;
  const float gcx = gx0 + 0.5f * gw;
  const float gcy = gy0 + 0.5f * gh;
  const float t0 = ((gcx - ecx) / ew) / 0.1f;
  const float t1 = ((gcy - ecy) / eh) / 0.1f;
  const float t2 = logf(gw / ew) / 0.2f;
  const float t3 = logf(gh / eh) / 0.2f;

  float* o_rois = out;                                   // [B,R,5]
  float* o_lab  = out + (size_t)kB * kR * 5;             // [B,R]
  float* o_tgt  = o_lab + (size_t)kB * kR;               // [B,R,4]
  float* o_iw   = o_tgt + (size_t)kB * kR * 4;           // [B,R,4]
  float* o_ow   = o_iw  + (size_t)kB * kR * 4;           // [B,R,4]
  const size_t p = (size_t)b * kR + pos;
  o_rois[p * 5 + 0] = (float)b;
  o_rois[p * 5 + 1] = bx0;
  o_rois[p * 5 + 2] = by0;
  o_rois[p * 5 + 3] = bx1;
  o_rois[p * 5 + 4] = by1;
  o_lab[p] = lab;
  o_tgt[p * 4 + 0] = t0 * fg4;
  o_tgt[p * 4 + 1] = t1 * fg4;
  o_tgt[p * 4 + 2] = t2 * fg4;
  o_tgt[p * 4 + 3] = t3 * fg4;
  o_iw[p * 4 + 0] = fg4; o_iw[p * 4 + 1] = fg4;
  o_iw[p * 4 + 2] = fg4; o_iw[p * 4 + 3] = fg4;
  o_ow[p * 4 + 0] = fg4; o_ow[p * 4 + 1] = fg4;
  o_ow[p * 4 + 2] = fg4; o_ow[p * 4 + 3] = fg4;
}

extern "C" void kernel_launch(void* const* d_in, const int* in_sizes, int n_in_args,
                              void* d_out, int out_size, void* d_ws, size_t ws_size,
                              hipStream_t stream) {
  (void)in_sizes; (void)n_in_args; (void)out_size; (void)ws_size;
  const float* all_rois = (const float*)d_in[0];  // [16,12000,5] fp32
  const float* gt_boxes = (const float*)d_in[1];  // [16,128,5] fp32
  float* out = (float*)d_out;

  char* ws = (char*)d_ws;
  int* asgn    = (int*)ws;                                 // kB*kM int
  unsigned* vb = (unsigned*)(ws + (size_t)kB * kM * 4);    // 2*kB*kM uint (16B aligned)
  int* nin     = (int*)(ws + (size_t)kB * kM * 4 * 3);     // 2*kB int
  int* topidx  = nin + 64;                                 // 2*kB*kR int

  dim3 gA((kM + 255) / 256, kB);
  k_prep<<<gA, 256, 0, stream>>>(all_rois, gt_boxes, asgn, vb);
  dim3 gB(2, kB);
  k_select<<<gB, 256, 0, stream>>>(vb, topidx, nin);
  k_finalize<<<kB, kR, 0, stream>>>(all_rois, gt_boxes, asgn, topidx, nin, out);
}